// Round 1
// baseline (438.208 us; speedup 1.0000x reference)
//
#include <hip/hip_runtime.h>

// out[b,o,i,l] = white_table[o,i, x[b,i,o,l]]
// B=8, IN=64, OUT=64, L=2048, LUT=256
// Input row x[b,i,o,:] and output row out[b,o,i,:] are both contiguous.

#define BATCH  8
#define IN_CH  64
#define OUT_CH 64
#define LEN    2048
#define LUTN   256

__global__ __launch_bounds__(256) void WhiteTranspose_28406913696445_kernel(
    const int* __restrict__ x,
    const float* __restrict__ table,
    float* __restrict__ out)
{
    __shared__ float lut[LUTN];

    const int row = blockIdx.x;          // row id in OUTPUT order: ((b*OUT + o)*IN + i)
    const int i = row & (IN_CH - 1);
    const int o = (row >> 6) & (OUT_CH - 1);
    const int b = row >> 12;

    // Stage this (o,i) LUT row into LDS: 256 floats, one per thread.
    lut[threadIdx.x] = table[(o * IN_CH + i) * LUTN + threadIdx.x];
    __syncthreads();

    // Contiguous rows on both sides.
    const int4* __restrict__ xin =
        (const int4*)(x + ((size_t)((b * IN_CH + i) * OUT_CH + o) * LEN));
    float4* __restrict__ dst =
        (float4*)(out + ((size_t)row * LEN));

    // LEN/4 = 512 int4 chunks; 256 threads -> 2 chunks per thread.
    #pragma unroll
    for (int it = 0; it < 2; ++it) {
        const int idx = threadIdx.x + it * 256;
        const int4 v = xin[idx];
        float4 r;
        r.x = lut[v.x];
        r.y = lut[v.y];
        r.z = lut[v.z];
        r.w = lut[v.w];
        dst[idx] = r;
    }
}

extern "C" void kernel_launch(void* const* d_in, const int* in_sizes, int n_in,
                              void* d_out, int out_size, void* d_ws, size_t ws_size,
                              hipStream_t stream) {
    const int*   x     = (const int*)d_in[0];
    const float* table = (const float*)d_in[1];
    float*       out   = (float*)d_out;

    const int n_rows = BATCH * OUT_CH * IN_CH;   // 32768 blocks
    WhiteTranspose_28406913696445_kernel<<<n_rows, 256, 0, stream>>>(x, table, out);
}